// Round 3
// baseline (260.795 us; speedup 1.0000x reference)
//
#include <hip/hip_runtime.h>
#include <hip/hip_bf16.h>

typedef __bf16 bf16;
typedef __bf16 bf16x4 __attribute__((ext_vector_type(4)));
typedef __bf16 bf16x8 __attribute__((ext_vector_type(8)));
typedef float f32x4 __attribute__((ext_vector_type(4)));

#define SEQ   2048
#define NBAT  4
#define DM    1024
#define NH    16
#define HD    64
#define E3    3072

// ---------------- fp32 -> bf16 convert ----------------
__global__ void cvt_bf16_kernel(const float* __restrict__ in, bf16* __restrict__ out, int n8) {
  int stride = gridDim.x * blockDim.x;
  for (int i = blockIdx.x * blockDim.x + threadIdx.x; i < n8; i += stride) {
    const float4* p = (const float4*)(in + (size_t)i * 8);
    float4 a = p[0];
    float4 b = p[1];
    bf16x8 o;
    o[0] = (bf16)a.x; o[1] = (bf16)a.y; o[2] = (bf16)a.z; o[3] = (bf16)a.w;
    o[4] = (bf16)b.x; o[5] = (bf16)b.y; o[6] = (bf16)b.z; o[7] = (bf16)b.w;
    *(bf16x8*)(out + (size_t)i * 8) = o;
  }
}

// ---------------- QKV projection GEMM: Z = X * W^T + b ----------------
#define BM 128
#define BN 128
#define BK 32
#define KSTEPS (DM / BK)

__global__ __launch_bounds__(256, 2) void qkv_gemm_kernel(
    const bf16* __restrict__ A, const bf16* __restrict__ B,
    const float* __restrict__ bias, bf16* __restrict__ Z)
{
  __shared__ bf16 sA[2][BM * BK];
  __shared__ bf16 sB[2][BN * BK];

  const int tid  = threadIdx.x;
  const int lane = tid & 63;
  const int w    = tid >> 6;
  const int wr   = w >> 1;
  const int wc   = w & 1;
  const int m0   = blockIdx.x * BM;
  const int n0   = blockIdx.y * BN;

  const f32x4 z4 = {0.f, 0.f, 0.f, 0.f};
  f32x4 acc[4][4];
#pragma unroll
  for (int i = 0; i < 4; ++i)
#pragma unroll
    for (int j = 0; j < 4; ++j)
      acc[i][j] = z4;

  const int srow = w * 32 + (lane >> 2);
  const int skk  = (lane & 3) * 8;
  const bf16* gA = A + (size_t)m0 * DM;
  const bf16* gB = B + (size_t)n0 * DM;

  auto stage = [&](int buf, int t) {
    const int k0 = t * BK;
#pragma unroll
    for (int c = 0; c < 2; ++c)
      __builtin_amdgcn_global_load_lds(
          (const __attribute__((address_space(1))) unsigned int*)(gA + (size_t)(srow + c * 16) * DM + k0 + skk),
          (__attribute__((address_space(3))) unsigned int*)(&sA[buf][w * 1024 + c * 512]),
          16, 0, 0);
#pragma unroll
    for (int c = 0; c < 2; ++c)
      __builtin_amdgcn_global_load_lds(
          (const __attribute__((address_space(1))) unsigned int*)(gB + (size_t)(srow + c * 16) * DM + k0 + skk),
          (__attribute__((address_space(3))) unsigned int*)(&sB[buf][w * 1024 + c * 512]),
          16, 0, 0);
  };

  stage(0, 0);
  int cur = 0;
  const int arow = wr * 64 + (lane & 15);
  const int brow = wc * 64 + (lane & 15);
  const int kf   = (lane >> 4) * 8;

  for (int t = 0; t < KSTEPS; ++t) {
    __syncthreads();
    if (t + 1 < KSTEPS) stage(cur ^ 1, t + 1);
    bf16x8 af[4], bfr[4];
#pragma unroll
    for (int i = 0; i < 4; ++i)
      af[i] = *(const bf16x8*)&sA[cur][(arow + i * 16) * BK + kf];
#pragma unroll
    for (int j = 0; j < 4; ++j)
      bfr[j] = *(const bf16x8*)&sB[cur][(brow + j * 16) * BK + kf];
#pragma unroll
    for (int i = 0; i < 4; ++i)
#pragma unroll
      for (int j = 0; j < 4; ++j)
        acc[i][j] = __builtin_amdgcn_mfma_f32_16x16x32_bf16(af[i], bfr[j], acc[i][j], 0, 0, 0);
    cur ^= 1;
  }

#pragma unroll
  for (int i = 0; i < 4; ++i) {
#pragma unroll
    for (int j = 0; j < 4; ++j) {
      const int col = n0 + wc * 64 + j * 16 + (lane & 15);
      const float bb = bias[col];
#pragma unroll
      for (int r = 0; r < 4; ++r) {
        const int row = m0 + wr * 64 + i * 16 + (lane >> 4) * 4 + r;
        Z[(size_t)row * E3 + col] = (bf16)(acc[i][j][r] + bb);
      }
    }
  }
}

// ---------------- causal flash attention ----------------
// Z layout per row: [K(0:1024) | Q(1024:2048) | V(2048:3072)], head h at +h*64
// Swapped QK^T: S^T = K·Q^T so q = lane&15 everywhere.
// PV uses the k-permutation k = c*32 + (j>>2)*16 + lhi*4 + (j&3):
//   B-frag (P^T) == the lane's own softmax registers, contiguous (no LDS!),
//   A-frag (V^T) == two b64 reads from sVT at permuted offsets.
#define QB 128
#define KB 64
#define KP 72   // padded LDS stride (bf16): 144B

__global__ __launch_bounds__(256, 4) void attn_kernel(
    const bf16* __restrict__ Z, float* __restrict__ out)
{
  __shared__ bf16 sK[KB][KP];
  __shared__ bf16 sVrow[KB][KP];
  __shared__ bf16 sVT[HD][KP];   // sVT[d][k]

  const int tid   = threadIdx.x;
  const int lane  = tid & 63;
  const int w     = tid >> 6;
  const int l15   = lane & 15;
  const int lhi   = lane >> 4;
  const int qtile = gridDim.x - 1 - blockIdx.x;   // longest blocks first
  const int h     = blockIdx.y;
  const int n     = blockIdx.z;
  const int q0    = qtile * QB;

  const size_t zb = (size_t)n * SEQ * E3;
  const int kcol0 = h * HD;
  const int qcol0 = DM + h * HD;
  const int vcol0 = 2 * DM + h * HD;

  // Q fragments (B-operand of swapped QK^T)
  bf16x8 qf[2][2];
#pragma unroll
  for (int qs = 0; qs < 2; ++qs) {
    const int qrow = q0 + w * 32 + qs * 16 + l15;
#pragma unroll
    for (int kk = 0; kk < 2; ++kk)
      qf[qs][kk] = *(const bf16x8*)&Z[zb + (size_t)qrow * E3 + qcol0 + kk * 32 + lhi * 8];
  }

  const f32x4 z4 = {0.f, 0.f, 0.f, 0.f};
  f32x4 accO[2][4];   // [qs][dt]: O^T[d=dt*16+lhi*4+r][q=l15]
#pragma unroll
  for (int qs = 0; qs < 2; ++qs)
#pragma unroll
    for (int dt = 0; dt < 4; ++dt) accO[qs][dt] = z4;
  float mrow[2] = {-1e30f, -1e30f};
  float lrow[2] = {0.f, 0.f};

  const float scale = 0.03125f;   // D^-0.5 = 1/32 (full model dim)
  const float L2E   = 1.4426950408889634f;

  // staging map
  const int c0row = tid >> 3;          // 0..31
  const int c0col = (tid & 7) * 8;
  // transpose map: thread owns column d=td, k rows [tk0, tk0+16)
  const int td  = tid & 63;
  const int tk0 = (tid >> 6) * 16;

  const int ntiles = 2 * qtile + 2;
  const int qwave  = q0 + w * 32;

  // register-held prefetch of next tile's K/V
  bf16x8 kpre[2], vpre[2];
  auto gload = [&](int t) {
    const size_t g0 = zb + (size_t)(t * KB) * E3;
#pragma unroll
    for (int c = 0; c < 2; ++c) {
      const int row = c0row + c * 32;
      kpre[c] = *(const bf16x8*)&Z[g0 + (size_t)row * E3 + kcol0 + c0col];
      vpre[c] = *(const bf16x8*)&Z[g0 + (size_t)row * E3 + vcol0 + c0col];
    }
  };
  gload(0);

  for (int t = 0; t < ntiles; ++t) {
    __syncthreads();               // previous tile's compute done; LDS free
#pragma unroll
    for (int c = 0; c < 2; ++c) {
      *(bf16x8*)&sK[c0row + c * 32][c0col]    = kpre[c];
      *(bf16x8*)&sVrow[c0row + c * 32][c0col] = vpre[c];
    }
    if (t + 1 < ntiles) gload(t + 1);   // issue early; lands during compute
    __syncthreads();               // staging visible

    // conflict-free-read V transpose: read a column, write rows of sVT
    {
      bf16 tv[16];
#pragma unroll
      for (int j = 0; j < 16; ++j) tv[j] = sVrow[tk0 + j][td];
      *(bf16x8*)&sVT[td][tk0]     = *(bf16x8*)&tv[0];
      *(bf16x8*)&sVT[td][tk0 + 8] = *(bf16x8*)&tv[8];
    }

    const bool active = (t * KB <= qwave + 31);
    bf16x8 pbv[2][2];   // [qs][c]: PV B-frag == softmax output, contiguous

    if (active) {
      // S^T = K·Q^T : C[k_local=lhi*4+r][q=l15] per kt
      f32x4 st[2][4];
#pragma unroll
      for (int qs = 0; qs < 2; ++qs)
#pragma unroll
        for (int kt = 0; kt < 4; ++kt) st[qs][kt] = z4;
#pragma unroll
      for (int kt = 0; kt < 4; ++kt)
#pragma unroll
        for (int kk = 0; kk < 2; ++kk) {
          bf16x8 kf = *(const bf16x8*)&sK[kt * 16 + l15][kk * 32 + lhi * 8];
#pragma unroll
          for (int qs = 0; qs < 2; ++qs)
            st[qs][kt] = __builtin_amdgcn_mfma_f32_16x16x32_bf16(kf, qf[qs][kk], st[qs][kt], 0, 0, 0);
        }

      const bool needmask = (t * KB + KB - 1) > qwave;

#pragma unroll
      for (int qs = 0; qs < 2; ++qs) {
        const int qg = qwave + qs * 16 + l15;
        float sv[16];
#pragma unroll
        for (int kt = 0; kt < 4; ++kt)
#pragma unroll
          for (int r = 0; r < 4; ++r) {
            float x = st[qs][kt][r] * scale;
            if (needmask) {
              const int kg = t * KB + kt * 16 + lhi * 4 + r;
              if (kg > qg) x = -1e30f;
            }
            sv[kt * 4 + r] = x;
          }
        float mx = sv[0];
#pragma unroll
        for (int i = 1; i < 16; ++i) mx = fmaxf(mx, sv[i]);
        mx = fmaxf(mx, __shfl_xor(mx, 16));
        mx = fmaxf(mx, __shfl_xor(mx, 32));
        const float mnew  = fmaxf(mrow[qs], mx);
        const float alpha = exp2f((mrow[qs] - mnew) * L2E);
        mrow[qs] = mnew;
        float ps = 0.f;
#pragma unroll
        for (int i = 0; i < 16; ++i) {
          const float p = exp2f((sv[i] - mnew) * L2E);
          pbv[qs][i >> 3][i & 7] = (bf16)p;
          ps += p;
        }
        ps += __shfl_xor(ps, 16);
        ps += __shfl_xor(ps, 32);
        lrow[qs] = lrow[qs] * alpha + ps;
#pragma unroll
        for (int dt = 0; dt < 4; ++dt) accO[qs][dt] *= alpha;
      }
    }

    __syncthreads();               // sVT complete (softmax overlapped the wait)

    if (active) {
      // O^T += V^T·P^T with the permuted k-map
#pragma unroll
      for (int c = 0; c < 2; ++c) {
#pragma unroll
        for (int dt = 0; dt < 4; ++dt) {
          const bf16x4 a0 = *(const bf16x4*)&sVT[dt * 16 + l15][c * 32 + lhi * 4];
          const bf16x4 a1 = *(const bf16x4*)&sVT[dt * 16 + l15][c * 32 + 16 + lhi * 4];
          bf16x8 av;
#pragma unroll
          for (int j = 0; j < 4; ++j) { av[j] = a0[j]; av[j + 4] = a1[j]; }
#pragma unroll
          for (int qs = 0; qs < 2; ++qs)
            accO[qs][dt] = __builtin_amdgcn_mfma_f32_16x16x32_bf16(av, pbv[qs][c], accO[qs][dt], 0, 0, 0);
        }
      }
    }
  }

  // epilogue: normalize, float4 stores (d = dt*16 + lhi*4 + r)
  const size_t ob = (size_t)n * SEQ * DM;
#pragma unroll
  for (int qs = 0; qs < 2; ++qs) {
    const float inv  = 1.f / lrow[qs];
    const int   qrow = qwave + qs * 16 + l15;
#pragma unroll
    for (int dt = 0; dt < 4; ++dt) {
      float4 o;
      o.x = accO[qs][dt][0] * inv;
      o.y = accO[qs][dt][1] * inv;
      o.z = accO[qs][dt][2] * inv;
      o.w = accO[qs][dt][3] * inv;
      *(float4*)&out[ob + (size_t)qrow * DM + h * HD + dt * 16 + lhi * 4] = o;
    }
  }
}

extern "C" void kernel_launch(void* const* d_in, const int* in_sizes, int n_in,
                              void* d_out, int out_size, void* d_ws, size_t ws_size,
                              hipStream_t stream) {
  const float* x    = (const float*)d_in[0];
  const float* W    = (const float*)d_in[1];
  const float* bias = (const float*)d_in[2];
  float* out = (float*)d_out;

  bf16* xb = (bf16*)d_ws;
  bf16* Wb = xb + (size_t)NBAT * SEQ * DM;
  bf16* Zb = Wb + (size_t)E3 * DM;

  cvt_bf16_kernel<<<1024, 256, 0, stream>>>(x, xb, NBAT * SEQ * DM / 8);
  cvt_bf16_kernel<<<512, 256, 0, stream>>>(W, Wb, E3 * DM / 8);

  dim3 g1(NBAT * SEQ / BM, E3 / BN);
  qkv_gemm_kernel<<<g1, 256, 0, stream>>>(xb, Wb, bias, Zb);

  dim3 g2(SEQ / QB, NH, NBAT);
  attn_kernel<<<g2, 256, 0, stream>>>(Zb, out);
}

// Round 4
// 237.343 us; speedup vs baseline: 1.0988x; 1.0988x over previous
//
#include <hip/hip_runtime.h>
#include <hip/hip_bf16.h>

typedef __bf16 bf16;
typedef __bf16 bf16x4 __attribute__((ext_vector_type(4)));
typedef __bf16 bf16x8 __attribute__((ext_vector_type(8)));
typedef float f32x4 __attribute__((ext_vector_type(4)));

#define SEQ   2048
#define NBAT  4
#define DM    1024
#define NH    16
#define HD    64
#define E3    3072

// ---------------- fp32 -> bf16 convert ----------------
__global__ void cvt_bf16_kernel(const float* __restrict__ in, bf16* __restrict__ out, int n8) {
  int stride = gridDim.x * blockDim.x;
  for (int i = blockIdx.x * blockDim.x + threadIdx.x; i < n8; i += stride) {
    const float4* p = (const float4*)(in + (size_t)i * 8);
    float4 a = p[0];
    float4 b = p[1];
    bf16x8 o;
    o[0] = (bf16)a.x; o[1] = (bf16)a.y; o[2] = (bf16)a.z; o[3] = (bf16)a.w;
    o[4] = (bf16)b.x; o[5] = (bf16)b.y; o[6] = (bf16)b.z; o[7] = (bf16)b.w;
    *(bf16x8*)(out + (size_t)i * 8) = o;
  }
}

// ---------------- QKV projection GEMM: Z = X * W^T + b ----------------
#define BM 128
#define BN 128
#define BK 32
#define KSTEPS (DM / BK)

__global__ __launch_bounds__(256, 2) void qkv_gemm_kernel(
    const bf16* __restrict__ A, const bf16* __restrict__ B,
    const float* __restrict__ bias, bf16* __restrict__ Z)
{
  __shared__ bf16 sA[2][BM * BK];
  __shared__ bf16 sB[2][BN * BK];

  const int tid  = threadIdx.x;
  const int lane = tid & 63;
  const int w    = tid >> 6;
  const int wr   = w >> 1;
  const int wc   = w & 1;
  const int m0   = blockIdx.x * BM;
  const int n0   = blockIdx.y * BN;

  const f32x4 z4 = {0.f, 0.f, 0.f, 0.f};
  f32x4 acc[4][4];
#pragma unroll
  for (int i = 0; i < 4; ++i)
#pragma unroll
    for (int j = 0; j < 4; ++j)
      acc[i][j] = z4;

  const int srow = w * 32 + (lane >> 2);
  const int skk  = (lane & 3) * 8;
  const bf16* gA = A + (size_t)m0 * DM;
  const bf16* gB = B + (size_t)n0 * DM;

  auto stage = [&](int buf, int t) {
    const int k0 = t * BK;
#pragma unroll
    for (int c = 0; c < 2; ++c)
      __builtin_amdgcn_global_load_lds(
          (const __attribute__((address_space(1))) unsigned int*)(gA + (size_t)(srow + c * 16) * DM + k0 + skk),
          (__attribute__((address_space(3))) unsigned int*)(&sA[buf][w * 1024 + c * 512]),
          16, 0, 0);
#pragma unroll
    for (int c = 0; c < 2; ++c)
      __builtin_amdgcn_global_load_lds(
          (const __attribute__((address_space(1))) unsigned int*)(gB + (size_t)(srow + c * 16) * DM + k0 + skk),
          (__attribute__((address_space(3))) unsigned int*)(&sB[buf][w * 1024 + c * 512]),
          16, 0, 0);
  };

  stage(0, 0);
  int cur = 0;
  const int arow = wr * 64 + (lane & 15);
  const int brow = wc * 64 + (lane & 15);
  const int kf   = (lane >> 4) * 8;

  for (int t = 0; t < KSTEPS; ++t) {
    __syncthreads();
    if (t + 1 < KSTEPS) stage(cur ^ 1, t + 1);
    bf16x8 af[4], bfr[4];
#pragma unroll
    for (int i = 0; i < 4; ++i)
      af[i] = *(const bf16x8*)&sA[cur][(arow + i * 16) * BK + kf];
#pragma unroll
    for (int j = 0; j < 4; ++j)
      bfr[j] = *(const bf16x8*)&sB[cur][(brow + j * 16) * BK + kf];
#pragma unroll
    for (int i = 0; i < 4; ++i)
#pragma unroll
      for (int j = 0; j < 4; ++j)
        acc[i][j] = __builtin_amdgcn_mfma_f32_16x16x32_bf16(af[i], bfr[j], acc[i][j], 0, 0, 0);
    cur ^= 1;
  }

#pragma unroll
  for (int i = 0; i < 4; ++i) {
#pragma unroll
    for (int j = 0; j < 4; ++j) {
      const int col = n0 + wc * 64 + j * 16 + (lane & 15);
      const float bb = bias[col];
#pragma unroll
      for (int r = 0; r < 4; ++r) {
        const int row = m0 + wr * 64 + i * 16 + (lane >> 4) * 4 + r;
        Z[(size_t)row * E3 + col] = (bf16)(acc[i][j][r] + bb);
      }
    }
  }
}

// ---------------- causal flash attention ----------------
// Z layout per row: [K(0:1024) | Q(1024:2048) | V(2048:3072)], head h at +h*64
// Swapped QK^T: S^T = K·Q^T so q = lane&15 everywhere.
// PV uses the k-permutation k = c*32 + (j>>2)*16 + lhi*4 + (j&3):
//   B-frag (P^T) == the lane's own softmax registers, contiguous (no LDS!),
//   A-frag (V^T) == two b64 reads from sVT at permuted offsets.
#define QB 128
#define KB 64
#define KP 72   // padded LDS stride (bf16): 144B

// NOTE: (256,4) caused a ~116-live-VGPR kernel to be squeezed to 64 VGPRs ->
// scratch spill (WRITE_SIZE 32->197 MB). Keep (256,2); LDS (27.6KB) still
// allows 5 blocks/CU, VGPRs ~3-4.
__global__ __launch_bounds__(256, 2) void attn_kernel(
    const bf16* __restrict__ Z, float* __restrict__ out)
{
  __shared__ bf16 sK[KB][KP];
  __shared__ bf16 sVrow[KB][KP];
  __shared__ bf16 sVT[HD][KP];   // sVT[d][k]

  const int tid   = threadIdx.x;
  const int lane  = tid & 63;
  const int w     = tid >> 6;
  const int l15   = lane & 15;
  const int lhi   = lane >> 4;
  const int qtile = gridDim.x - 1 - blockIdx.x;   // longest blocks first
  const int h     = blockIdx.y;
  const int n     = blockIdx.z;
  const int q0    = qtile * QB;

  const size_t zb = (size_t)n * SEQ * E3;
  const int kcol0 = h * HD;
  const int qcol0 = DM + h * HD;
  const int vcol0 = 2 * DM + h * HD;

  // Q fragments (B-operand of swapped QK^T)
  bf16x8 qf[2][2];
#pragma unroll
  for (int qs = 0; qs < 2; ++qs) {
    const int qrow = q0 + w * 32 + qs * 16 + l15;
#pragma unroll
    for (int kk = 0; kk < 2; ++kk)
      qf[qs][kk] = *(const bf16x8*)&Z[zb + (size_t)qrow * E3 + qcol0 + kk * 32 + lhi * 8];
  }

  const f32x4 z4 = {0.f, 0.f, 0.f, 0.f};
  f32x4 accO[2][4];   // [qs][dt]: O^T[d=dt*16+lhi*4+r][q=l15]
#pragma unroll
  for (int qs = 0; qs < 2; ++qs)
#pragma unroll
    for (int dt = 0; dt < 4; ++dt) accO[qs][dt] = z4;
  float mrow[2] = {-1e30f, -1e30f};
  float lrow[2] = {0.f, 0.f};

  const float scale = 0.03125f;   // D^-0.5 = 1/32 (full model dim)
  const float L2E   = 1.4426950408889634f;

  // staging map
  const int c0row = tid >> 3;          // 0..31
  const int c0col = (tid & 7) * 8;
  // transpose map: thread owns column d=td, k rows [tk0, tk0+16)
  const int td  = tid & 63;
  const int tk0 = (tid >> 6) * 16;

  const int ntiles = 2 * qtile + 2;
  const int qwave  = q0 + w * 32;

  // register-held prefetch of next tile's K/V
  bf16x8 kpre[2], vpre[2];
  auto gload = [&](int t) {
    const size_t g0 = zb + (size_t)(t * KB) * E3;
#pragma unroll
    for (int c = 0; c < 2; ++c) {
      const int row = c0row + c * 32;
      kpre[c] = *(const bf16x8*)&Z[g0 + (size_t)row * E3 + kcol0 + c0col];
      vpre[c] = *(const bf16x8*)&Z[g0 + (size_t)row * E3 + vcol0 + c0col];
    }
  };
  gload(0);

  for (int t = 0; t < ntiles; ++t) {
    __syncthreads();               // previous tile's compute done; LDS free
#pragma unroll
    for (int c = 0; c < 2; ++c) {
      *(bf16x8*)&sK[c0row + c * 32][c0col]    = kpre[c];
      *(bf16x8*)&sVrow[c0row + c * 32][c0col] = vpre[c];
    }
    if (t + 1 < ntiles) gload(t + 1);   // issue early; lands during compute
    __syncthreads();               // staging visible

    // conflict-free-read V transpose: read a column, write rows of sVT
    {
      bf16 tv[16];
#pragma unroll
      for (int j = 0; j < 16; ++j) tv[j] = sVrow[tk0 + j][td];
      *(bf16x8*)&sVT[td][tk0]     = *(bf16x8*)&tv[0];
      *(bf16x8*)&sVT[td][tk0 + 8] = *(bf16x8*)&tv[8];
    }

    const bool active = (t * KB <= qwave + 31);
    bf16x8 pbv[2][2];   // [qs][c]: PV B-frag == softmax output, contiguous

    if (active) {
      // S^T = K·Q^T : C[k_local=lhi*4+r][q=l15] per kt
      f32x4 st[2][4];
#pragma unroll
      for (int qs = 0; qs < 2; ++qs)
#pragma unroll
        for (int kt = 0; kt < 4; ++kt) st[qs][kt] = z4;
#pragma unroll
      for (int kt = 0; kt < 4; ++kt)
#pragma unroll
        for (int kk = 0; kk < 2; ++kk) {
          bf16x8 kf = *(const bf16x8*)&sK[kt * 16 + l15][kk * 32 + lhi * 8];
#pragma unroll
          for (int qs = 0; qs < 2; ++qs)
            st[qs][kt] = __builtin_amdgcn_mfma_f32_16x16x32_bf16(kf, qf[qs][kk], st[qs][kt], 0, 0, 0);
        }

      const bool needmask = (t * KB + KB - 1) > qwave;

#pragma unroll
      for (int qs = 0; qs < 2; ++qs) {
        const int qg = qwave + qs * 16 + l15;
        float sv[16];
#pragma unroll
        for (int kt = 0; kt < 4; ++kt)
#pragma unroll
          for (int r = 0; r < 4; ++r) {
            float x = st[qs][kt][r] * scale;
            if (needmask) {
              const int kg = t * KB + kt * 16 + lhi * 4 + r;
              if (kg > qg) x = -1e30f;
            }
            sv[kt * 4 + r] = x;
          }
        float mx = sv[0];
#pragma unroll
        for (int i = 1; i < 16; ++i) mx = fmaxf(mx, sv[i]);
        mx = fmaxf(mx, __shfl_xor(mx, 16));
        mx = fmaxf(mx, __shfl_xor(mx, 32));
        const float mnew  = fmaxf(mrow[qs], mx);
        const float alpha = exp2f((mrow[qs] - mnew) * L2E);
        mrow[qs] = mnew;
        float ps = 0.f;
#pragma unroll
        for (int i = 0; i < 16; ++i) {
          const float p = exp2f((sv[i] - mnew) * L2E);
          pbv[qs][i >> 3][i & 7] = (bf16)p;
          ps += p;
        }
        ps += __shfl_xor(ps, 16);
        ps += __shfl_xor(ps, 32);
        lrow[qs] = lrow[qs] * alpha + ps;
#pragma unroll
        for (int dt = 0; dt < 4; ++dt) accO[qs][dt] *= alpha;
      }
    }

    __syncthreads();               // sVT complete (softmax overlapped the wait)

    if (active) {
      // O^T += V^T·P^T with the permuted k-map
#pragma unroll
      for (int c = 0; c < 2; ++c) {
#pragma unroll
        for (int dt = 0; dt < 4; ++dt) {
          const bf16x4 a0 = *(const bf16x4*)&sVT[dt * 16 + l15][c * 32 + lhi * 4];
          const bf16x4 a1 = *(const bf16x4*)&sVT[dt * 16 + l15][c * 32 + 16 + lhi * 4];
          bf16x8 av;
#pragma unroll
          for (int j = 0; j < 4; ++j) { av[j] = a0[j]; av[j + 4] = a1[j]; }
#pragma unroll
          for (int qs = 0; qs < 2; ++qs)
            accO[qs][dt] = __builtin_amdgcn_mfma_f32_16x16x32_bf16(av, pbv[qs][c], accO[qs][dt], 0, 0, 0);
        }
      }
    }
  }

  // epilogue: normalize, float4 stores (d = dt*16 + lhi*4 + r)
  const size_t ob = (size_t)n * SEQ * DM;
#pragma unroll
  for (int qs = 0; qs < 2; ++qs) {
    const float inv  = 1.f / lrow[qs];
    const int   qrow = qwave + qs * 16 + l15;
#pragma unroll
    for (int dt = 0; dt < 4; ++dt) {
      float4 o;
      o.x = accO[qs][dt][0] * inv;
      o.y = accO[qs][dt][1] * inv;
      o.z = accO[qs][dt][2] * inv;
      o.w = accO[qs][dt][3] * inv;
      *(float4*)&out[ob + (size_t)qrow * DM + h * HD + dt * 16 + lhi * 4] = o;
    }
  }
}

extern "C" void kernel_launch(void* const* d_in, const int* in_sizes, int n_in,
                              void* d_out, int out_size, void* d_ws, size_t ws_size,
                              hipStream_t stream) {
  const float* x    = (const float*)d_in[0];
  const float* W    = (const float*)d_in[1];
  const float* bias = (const float*)d_in[2];
  float* out = (float*)d_out;

  bf16* xb = (bf16*)d_ws;
  bf16* Wb = xb + (size_t)NBAT * SEQ * DM;
  bf16* Zb = Wb + (size_t)E3 * DM;

  cvt_bf16_kernel<<<1024, 256, 0, stream>>>(x, xb, NBAT * SEQ * DM / 8);
  cvt_bf16_kernel<<<512, 256, 0, stream>>>(W, Wb, E3 * DM / 8);

  dim3 g1(NBAT * SEQ / BM, E3 / BN);
  qkv_gemm_kernel<<<g1, 256, 0, stream>>>(xb, Wb, bias, Zb);

  dim3 g2(SEQ / QB, NH, NBAT);
  attn_kernel<<<g2, 256, 0, stream>>>(Zb, out);
}

// Round 6
// 224.837 us; speedup vs baseline: 1.1599x; 1.0556x over previous
//
#include <hip/hip_runtime.h>
#include <hip/hip_bf16.h>

typedef __bf16 bf16;
typedef __bf16 bf16x4 __attribute__((ext_vector_type(4)));
typedef __bf16 bf16x8 __attribute__((ext_vector_type(8)));
typedef float f32x4 __attribute__((ext_vector_type(4)));
typedef unsigned int u32x2 __attribute__((ext_vector_type(2)));
typedef unsigned int u32x4 __attribute__((ext_vector_type(4)));

#define SEQ   2048
#define NBAT  4
#define DM    1024
#define NH    16
#define HD    64
#define E3    3072

// ---------------- fp32 -> bf16 convert ----------------
__global__ void cvt_bf16_kernel(const float* __restrict__ in, bf16* __restrict__ out, int n8) {
  int stride = gridDim.x * blockDim.x;
  for (int i = blockIdx.x * blockDim.x + threadIdx.x; i < n8; i += stride) {
    const float4* p = (const float4*)(in + (size_t)i * 8);
    float4 a = p[0];
    float4 b = p[1];
    bf16x8 o;
    o[0] = (bf16)a.x; o[1] = (bf16)a.y; o[2] = (bf16)a.z; o[3] = (bf16)a.w;
    o[4] = (bf16)b.x; o[5] = (bf16)b.y; o[6] = (bf16)b.z; o[7] = (bf16)b.w;
    *(bf16x8*)(out + (size_t)i * 8) = o;
  }
}

// ---------------- QKV projection GEMM: Z = X * W^T + b ----------------
#define BM 128
#define BN 128
#define BK 32
#define KSTEPS (DM / BK)

__global__ __launch_bounds__(256, 2) void qkv_gemm_kernel(
    const bf16* __restrict__ A, const bf16* __restrict__ B,
    const float* __restrict__ bias, bf16* __restrict__ Z)
{
  __shared__ bf16 sA[2][BM * BK];
  __shared__ bf16 sB[2][BN * BK];

  const int tid  = threadIdx.x;
  const int lane = tid & 63;
  const int w    = tid >> 6;
  const int wr   = w >> 1;
  const int wc   = w & 1;
  const int m0   = blockIdx.x * BM;
  const int n0   = blockIdx.y * BN;

  const f32x4 z4 = {0.f, 0.f, 0.f, 0.f};
  f32x4 acc[4][4];
#pragma unroll
  for (int i = 0; i < 4; ++i)
#pragma unroll
    for (int j = 0; j < 4; ++j)
      acc[i][j] = z4;

  const int srow = w * 32 + (lane >> 2);
  const int skk  = (lane & 3) * 8;
  const bf16* gA = A + (size_t)m0 * DM;
  const bf16* gB = B + (size_t)n0 * DM;

  auto stage = [&](int buf, int t) {
    const int k0 = t * BK;
#pragma unroll
    for (int c = 0; c < 2; ++c)
      __builtin_amdgcn_global_load_lds(
          (const __attribute__((address_space(1))) unsigned int*)(gA + (size_t)(srow + c * 16) * DM + k0 + skk),
          (__attribute__((address_space(3))) unsigned int*)(&sA[buf][w * 1024 + c * 512]),
          16, 0, 0);
#pragma unroll
    for (int c = 0; c < 2; ++c)
      __builtin_amdgcn_global_load_lds(
          (const __attribute__((address_space(1))) unsigned int*)(gB + (size_t)(srow + c * 16) * DM + k0 + skk),
          (__attribute__((address_space(3))) unsigned int*)(&sB[buf][w * 1024 + c * 512]),
          16, 0, 0);
  };

  stage(0, 0);
  int cur = 0;
  const int arow = wr * 64 + (lane & 15);
  const int brow = wc * 64 + (lane & 15);
  const int kf   = (lane >> 4) * 8;

  for (int t = 0; t < KSTEPS; ++t) {
    __syncthreads();
    if (t + 1 < KSTEPS) stage(cur ^ 1, t + 1);
    bf16x8 af[4], bfr[4];
#pragma unroll
    for (int i = 0; i < 4; ++i)
      af[i] = *(const bf16x8*)&sA[cur][(arow + i * 16) * BK + kf];
#pragma unroll
    for (int j = 0; j < 4; ++j)
      bfr[j] = *(const bf16x8*)&sB[cur][(brow + j * 16) * BK + kf];
#pragma unroll
    for (int i = 0; i < 4; ++i)
#pragma unroll
      for (int j = 0; j < 4; ++j)
        acc[i][j] = __builtin_amdgcn_mfma_f32_16x16x32_bf16(af[i], bfr[j], acc[i][j], 0, 0, 0);
    cur ^= 1;
  }

#pragma unroll
  for (int i = 0; i < 4; ++i) {
#pragma unroll
    for (int j = 0; j < 4; ++j) {
      const int col = n0 + wc * 64 + j * 16 + (lane & 15);
      const float bb = bias[col];
#pragma unroll
      for (int r = 0; r < 4; ++r) {
        const int row = m0 + wr * 64 + i * 16 + (lane >> 4) * 4 + r;
        Z[(size_t)row * E3 + col] = (bf16)(acc[i][j][r] + bb);
      }
    }
  }
}

// ---------------- causal flash attention ----------------
// Swapped QK^T: S^T = K·Q^T so q = lane&15 everywhere.
// PV k-permutation k = c*32 + (j>>2)*16 + lhi*4 + (j&3):
//   B-frag (P^T) == lane's own softmax registers (no LDS round-trip),
//   A-frag (V^T) == two b64 reads from sVT.
// Softmax denominator via ones-MFMA (accL); defer-max rescale (THR=4).
#define QB 128
#define KB 64
#define KP 72   // padded LDS stride (bf16): 144B

__global__ __launch_bounds__(256, 2) void attn_kernel(
    const bf16* __restrict__ Z, float* __restrict__ out)
{
  __shared__ bf16 sK[KB][KP];
  __shared__ bf16 sVrow[KB][KP];
  __shared__ bf16 sVT[HD][KP];   // sVT[d][k]

  const int tid   = threadIdx.x;
  const int lane  = tid & 63;
  const int w     = tid >> 6;
  const int l15   = lane & 15;
  const int lhi   = lane >> 4;
  const int qtile = gridDim.x - 1 - blockIdx.x;   // longest blocks first
  const int h     = blockIdx.y;
  const int n     = blockIdx.z;
  const int q0    = qtile * QB;

  const size_t zb = (size_t)n * SEQ * E3;
  const int kcol0 = h * HD;
  const int qcol0 = DM + h * HD;
  const int vcol0 = 2 * DM + h * HD;

  // Q fragments (B-operand of swapped QK^T)
  bf16x8 qf[2][2];
#pragma unroll
  for (int qs = 0; qs < 2; ++qs) {
    const int qrow = q0 + w * 32 + qs * 16 + l15;
#pragma unroll
    for (int kk = 0; kk < 2; ++kk)
      qf[qs][kk] = *(const bf16x8*)&Z[zb + (size_t)qrow * E3 + qcol0 + kk * 32 + lhi * 8];
  }

  const f32x4 z4 = {0.f, 0.f, 0.f, 0.f};
  f32x4 accO[2][4];   // [qs][dt]: O^T[d=dt*16+lhi*4+r][q=l15]
  f32x4 accL[2];      // ones-MFMA row-sum accumulator (all 4 rows equal)
#pragma unroll
  for (int qs = 0; qs < 2; ++qs) {
#pragma unroll
    for (int dt = 0; dt < 4; ++dt) accO[qs][dt] = z4;
    accL[qs] = z4;
  }
  float mrow[2] = {-1e30f, -1e30f};

  const float scale = 0.03125f;   // D^-0.5 = 1/32 (full model dim)
  const float L2E   = 1.4426950408889634f;
  const float SL2E  = scale * L2E;
  const float DEFER = 4.0f;       // skip rescale while mx <= m + 4 (P <= e^4)

  const u32x4 onesu = {0x3F803F80u, 0x3F803F80u, 0x3F803F80u, 0x3F803F80u};
  const bf16x8 onesf = __builtin_bit_cast(bf16x8, onesu);

  // staging map
  const int c0row = tid >> 3;          // 0..31
  const int c0col = (tid & 7) * 8;
  // transpose map: thread owns column d=td, k rows [tk0, tk0+16)
  const int td  = tid & 63;
  const int tk0 = (tid >> 6) * 16;

  const int ntiles = 2 * qtile + 2;
  const int qwave  = q0 + w * 32;

  // register-held prefetch of next tile's K/V
  bf16x8 kpre[2], vpre[2];
  auto gload = [&](int t) {
    const size_t g0 = zb + (size_t)(t * KB) * E3;
#pragma unroll
    for (int c = 0; c < 2; ++c) {
      const int row = c0row + c * 32;
      kpre[c] = *(const bf16x8*)&Z[g0 + (size_t)row * E3 + kcol0 + c0col];
      vpre[c] = *(const bf16x8*)&Z[g0 + (size_t)row * E3 + vcol0 + c0col];
    }
  };
  gload(0);

  for (int t = 0; t < ntiles; ++t) {
    __syncthreads();               // previous tile's compute done; LDS free
#pragma unroll
    for (int c = 0; c < 2; ++c) {
      *(bf16x8*)&sK[c0row + c * 32][c0col]    = kpre[c];
      *(bf16x8*)&sVrow[c0row + c * 32][c0col] = vpre[c];
    }
    if (t + 1 < ntiles) gload(t + 1);   // issue early; lands during compute
    __syncthreads();               // staging visible

    // conflict-free-read V transpose: read a column, write rows of sVT
    {
      bf16 tv[16];
#pragma unroll
      for (int j = 0; j < 16; ++j) tv[j] = sVrow[tk0 + j][td];
      *(bf16x8*)&sVT[td][tk0]     = *(bf16x8*)&tv[0];
      *(bf16x8*)&sVT[td][tk0 + 8] = *(bf16x8*)&tv[8];
    }

    const bool active = (t * KB <= qwave + 31);
    union PB { unsigned int u[4]; bf16x8 v; };
    PB pb[2][2];   // [qs][c]: PV B-frag == packed softmax output

    if (active) {
      // S^T = K·Q^T : C[k_local=lhi*4+r][q=l15] per kt
      f32x4 st[2][4];
#pragma unroll
      for (int qs = 0; qs < 2; ++qs)
#pragma unroll
        for (int kt = 0; kt < 4; ++kt) st[qs][kt] = z4;
#pragma unroll
      for (int kt = 0; kt < 4; ++kt)
#pragma unroll
        for (int kk = 0; kk < 2; ++kk) {
          bf16x8 kf = *(const bf16x8*)&sK[kt * 16 + l15][kk * 32 + lhi * 8];
#pragma unroll
          for (int qs = 0; qs < 2; ++qs)
            st[qs][kt] = __builtin_amdgcn_mfma_f32_16x16x32_bf16(kf, qf[qs][kk], st[qs][kt], 0, 0, 0);
        }

      const bool needmask = (t * KB + KB - 1) > qwave;
      float sv[2][16];
      float mxs[2];

#pragma unroll
      for (int qs = 0; qs < 2; ++qs) {
#pragma unroll
        for (int i = 0; i < 16; ++i) sv[qs][i] = st[qs][i >> 2][i & 3];
        if (needmask) {
          const int qg = qwave + qs * 16 + l15;
#pragma unroll
          for (int i = 0; i < 16; ++i) {
            const int kg = t * KB + (i >> 2) * 16 + lhi * 4 + (i & 3);
            if (kg > qg) sv[qs][i] = -1e32f;
          }
        }
        // raw max tree, then one scale
        float m0 = fmaxf(sv[qs][0], sv[qs][1]);
        float m1 = fmaxf(sv[qs][2], sv[qs][3]);
        float m2 = fmaxf(sv[qs][4], sv[qs][5]);
        float m3 = fmaxf(sv[qs][6], sv[qs][7]);
        float m4 = fmaxf(sv[qs][8], sv[qs][9]);
        float m5 = fmaxf(sv[qs][10], sv[qs][11]);
        float m6 = fmaxf(sv[qs][12], sv[qs][13]);
        float m7 = fmaxf(sv[qs][14], sv[qs][15]);
        float mr = fmaxf(fmaxf(fmaxf(m0, m1), fmaxf(m2, m3)),
                         fmaxf(fmaxf(m4, m5), fmaxf(m6, m7)));
        mr = fmaxf(mr, __shfl_xor(mr, 16));
        mr = fmaxf(mr, __shfl_xor(mr, 32));
        mxs[qs] = mr * scale;
      }

      // defer-max: only rescale when some row's max actually outgrew m+THR
      const bool grow = (mxs[0] > mrow[0] + DEFER) || (mxs[1] > mrow[1] + DEFER);
      if (__any(grow)) {
#pragma unroll
        for (int qs = 0; qs < 2; ++qs) {
          const float mnew  = fmaxf(mrow[qs], mxs[qs]);
          const float alpha = exp2f((mrow[qs] - mnew) * L2E);
          mrow[qs] = mnew;
#pragma unroll
          for (int dt = 0; dt < 4; ++dt) accO[qs][dt] *= alpha;
          accL[qs] *= alpha;
        }
      }

      // p = exp2(fma(s_raw, scale*log2e, -m*log2e)), packed in pairs
#pragma unroll
      for (int qs = 0; qs < 2; ++qs) {
        const float mm = -mrow[qs] * L2E;
#pragma unroll
        for (int c = 0; c < 2; ++c)
#pragma unroll
          for (int i = 0; i < 4; ++i) {
            const float p0 = exp2f(fmaf(sv[qs][c * 8 + 2 * i],     SL2E, mm));
            const float p1 = exp2f(fmaf(sv[qs][c * 8 + 2 * i + 1], SL2E, mm));
            const bf16 b0 = (bf16)p0;
            const bf16 b1 = (bf16)p1;
            pb[qs][c].u[i] = (unsigned int)__builtin_bit_cast(unsigned short, b0)
                           | ((unsigned int)__builtin_bit_cast(unsigned short, b1) << 16);
          }
      }
    }

    __syncthreads();               // sVT complete (softmax overlapped the wait)

    if (active) {
      // denominator: accL += ones * P^T  (rescale folds in automatically)
#pragma unroll
      for (int c = 0; c < 2; ++c)
#pragma unroll
        for (int qs = 0; qs < 2; ++qs)
          accL[qs] = __builtin_amdgcn_mfma_f32_16x16x32_bf16(onesf, pb[qs][c].v, accL[qs], 0, 0, 0);

      // O^T += V^T·P^T with the permuted k-map
#pragma unroll
      for (int c = 0; c < 2; ++c) {
#pragma unroll
        for (int dt = 0; dt < 4; ++dt) {
          const u32x2 a0 = *(const u32x2*)&sVT[dt * 16 + l15][c * 32 + lhi * 4];
          const u32x2 a1 = *(const u32x2*)&sVT[dt * 16 + l15][c * 32 + 16 + lhi * 4];
          const u32x4 avu = {a0[0], a0[1], a1[0], a1[1]};
          const bf16x8 av = __builtin_bit_cast(bf16x8, avu);
#pragma unroll
          for (int qs = 0; qs < 2; ++qs)
            accO[qs][dt] = __builtin_amdgcn_mfma_f32_16x16x32_bf16(av, pb[qs][c].v, accO[qs][dt], 0, 0, 0);
        }
      }
    }
  }

  // epilogue: normalize, float4 stores (d = dt*16 + lhi*4 + r)
  const size_t ob = (size_t)n * SEQ * DM;
#pragma unroll
  for (int qs = 0; qs < 2; ++qs) {
    const float inv  = 1.f / accL[qs][0];
    const int   qrow = qwave + qs * 16 + l15;
#pragma unroll
    for (int dt = 0; dt < 4; ++dt) {
      float4 o;
      o.x = accO[qs][dt][0] * inv;
      o.y = accO[qs][dt][1] * inv;
      o.z = accO[qs][dt][2] * inv;
      o.w = accO[qs][dt][3] * inv;
      *(float4*)&out[ob + (size_t)qrow * DM + h * HD + dt * 16 + lhi * 4] = o;
    }
  }
}

extern "C" void kernel_launch(void* const* d_in, const int* in_sizes, int n_in,
                              void* d_out, int out_size, void* d_ws, size_t ws_size,
                              hipStream_t stream) {
  const float* x    = (const float*)d_in[0];
  const float* W    = (const float*)d_in[1];
  const float* bias = (const float*)d_in[2];
  float* out = (float*)d_out;

  bf16* xb = (bf16*)d_ws;
  bf16* Wb = xb + (size_t)NBAT * SEQ * DM;
  bf16* Zb = Wb + (size_t)E3 * DM;

  cvt_bf16_kernel<<<1024, 256, 0, stream>>>(x, xb, NBAT * SEQ * DM / 8);
  cvt_bf16_kernel<<<512, 256, 0, stream>>>(W, Wb, E3 * DM / 8);

  dim3 g1(NBAT * SEQ / BM, E3 / BN);
  qkv_gemm_kernel<<<g1, 256, 0, stream>>>(xb, Wb, bias, Zb);

  dim3 g2(SEQ / QB, NH, NBAT);
  attn_kernel<<<g2, 256, 0, stream>>>(Zb, out);
}

// Round 7
// 175.549 us; speedup vs baseline: 1.4856x; 1.2808x over previous
//
#include <hip/hip_runtime.h>
#include <hip/hip_bf16.h>

typedef __bf16 bf16;
typedef __bf16 bf16x4 __attribute__((ext_vector_type(4)));
typedef __bf16 bf16x8 __attribute__((ext_vector_type(8)));
typedef float f32x4 __attribute__((ext_vector_type(4)));
typedef unsigned int u32x2 __attribute__((ext_vector_type(2)));
typedef unsigned int u32x4 __attribute__((ext_vector_type(4)));

#define SEQ   2048
#define NBAT  4
#define DM    1024
#define NH    16
#define HD    64
#define E3    3072

// ---------------- fp32 -> bf16 convert ----------------
__global__ void cvt_bf16_kernel(const float* __restrict__ in, bf16* __restrict__ out, int n8) {
  int stride = gridDim.x * blockDim.x;
  for (int i = blockIdx.x * blockDim.x + threadIdx.x; i < n8; i += stride) {
    const float4* p = (const float4*)(in + (size_t)i * 8);
    float4 a = p[0];
    float4 b = p[1];
    bf16x8 o;
    o[0] = (bf16)a.x; o[1] = (bf16)a.y; o[2] = (bf16)a.z; o[3] = (bf16)a.w;
    o[4] = (bf16)b.x; o[5] = (bf16)b.y; o[6] = (bf16)b.z; o[7] = (bf16)b.w;
    *(bf16x8*)(out + (size_t)i * 8) = o;
  }
}

// ---------------- QKV projection GEMM: Z = X * W^T + b ----------------
#define BM 128
#define BN 128
#define BK 32
#define KSTEPS (DM / BK)

__global__ __launch_bounds__(256, 2) void qkv_gemm_kernel(
    const bf16* __restrict__ A, const bf16* __restrict__ B,
    const float* __restrict__ bias, bf16* __restrict__ Z)
{
  __shared__ bf16 sA[2][BM * BK];
  __shared__ bf16 sB[2][BN * BK];

  const int tid  = threadIdx.x;
  const int lane = tid & 63;
  const int w    = tid >> 6;
  const int wr   = w >> 1;
  const int wc   = w & 1;
  const int m0   = blockIdx.x * BM;
  const int n0   = blockIdx.y * BN;

  const f32x4 z4 = {0.f, 0.f, 0.f, 0.f};
  f32x4 acc[4][4];
#pragma unroll
  for (int i = 0; i < 4; ++i)
#pragma unroll
    for (int j = 0; j < 4; ++j)
      acc[i][j] = z4;

  const int srow = w * 32 + (lane >> 2);
  const int skk  = (lane & 3) * 8;
  const bf16* gA = A + (size_t)m0 * DM;
  const bf16* gB = B + (size_t)n0 * DM;

  auto stage = [&](int buf, int t) {
    const int k0 = t * BK;
#pragma unroll
    for (int c = 0; c < 2; ++c)
      __builtin_amdgcn_global_load_lds(
          (const __attribute__((address_space(1))) unsigned int*)(gA + (size_t)(srow + c * 16) * DM + k0 + skk),
          (__attribute__((address_space(3))) unsigned int*)(&sA[buf][w * 1024 + c * 512]),
          16, 0, 0);
#pragma unroll
    for (int c = 0; c < 2; ++c)
      __builtin_amdgcn_global_load_lds(
          (const __attribute__((address_space(1))) unsigned int*)(gB + (size_t)(srow + c * 16) * DM + k0 + skk),
          (__attribute__((address_space(3))) unsigned int*)(&sB[buf][w * 1024 + c * 512]),
          16, 0, 0);
  };

  stage(0, 0);
  int cur = 0;
  const int arow = wr * 64 + (lane & 15);
  const int brow = wc * 64 + (lane & 15);
  const int kf   = (lane >> 4) * 8;

  for (int t = 0; t < KSTEPS; ++t) {
    __syncthreads();
    if (t + 1 < KSTEPS) stage(cur ^ 1, t + 1);
    bf16x8 af[4], bfr[4];
#pragma unroll
    for (int i = 0; i < 4; ++i)
      af[i] = *(const bf16x8*)&sA[cur][(arow + i * 16) * BK + kf];
#pragma unroll
    for (int j = 0; j < 4; ++j)
      bfr[j] = *(const bf16x8*)&sB[cur][(brow + j * 16) * BK + kf];
#pragma unroll
    for (int i = 0; i < 4; ++i)
#pragma unroll
      for (int j = 0; j < 4; ++j)
        acc[i][j] = __builtin_amdgcn_mfma_f32_16x16x32_bf16(af[i], bfr[j], acc[i][j], 0, 0, 0);
    cur ^= 1;
  }

#pragma unroll
  for (int i = 0; i < 4; ++i) {
#pragma unroll
    for (int j = 0; j < 4; ++j) {
      const int col = n0 + wc * 64 + j * 16 + (lane & 15);
      const float bb = bias[col];
#pragma unroll
      for (int r = 0; r < 4; ++r) {
        const int row = m0 + wr * 64 + i * 16 + (lane >> 4) * 4 + r;
        Z[(size_t)row * E3 + col] = (bf16)(acc[i][j][r] + bb);
      }
    }
  }
}

// ---------------- causal flash attention ----------------
// Swapped QK^T: S^T = K·Q^T so q = lane&15 everywhere.
// PV k-permutation k = c*32 + (j>>2)*16 + lhi*4 + (j&3):
//   B-frag (P^T) == lane's own softmax registers, A-frag (V^T) from sVT.
// Pair-scheduled causal: block b does qtile b then qtile 15-b -> uniform 34
// tile-iterations per block. Single barrier per tile: double-buffered sK/sVT,
// V^T written directly from prefetch registers (no sVrow, no transpose pass).
#define QB 128
#define KB 64
#define KPK 72   // sK stride (bf16): 144B, b128-aligned
#define KPV 68   // sVT stride (bf16): 136B, b64-aligned

__global__ __launch_bounds__(256, 2) void attn_kernel(
    const bf16* __restrict__ Z, float* __restrict__ out)
{
  __shared__ bf16 sK[2][KB][KPK];
  __shared__ bf16 sVT[2][HD][KPV];   // sVT[buf][d][k]

  const int tid   = threadIdx.x;
  const int lane  = tid & 63;
  const int w     = tid >> 6;
  const int l15   = lane & 15;
  const int lhi   = lane >> 4;
  const int h     = blockIdx.y;
  const int n     = blockIdx.z;

  const size_t zb = (size_t)n * SEQ * E3;
  const int kcol0 = h * HD;
  const int qcol0 = DM + h * HD;
  const int vcol0 = 2 * DM + h * HD;

  const f32x4 z4 = {0.f, 0.f, 0.f, 0.f};
  const float scale = 0.03125f;   // D^-0.5 = 1/32 (full model dim)
  const float L2E   = 1.4426950408889634f;
  const float SL2E  = scale * L2E;
  const float DEFER = 4.0f;

  const u32x4 onesu = {0x3F803F80u, 0x3F803F80u, 0x3F803F80u, 0x3F803F80u};
  const bf16x8 onesf = __builtin_bit_cast(bf16x8, onesu);

  // staging map: thread owns k-rows {c0row, c0row+32}, d-cols c0col..c0col+7
  const int c0row = tid >> 3;          // 0..31
  const int c0col = (tid & 7) * 8;

  const size_t ob = (size_t)n * SEQ * DM;

  bf16x8 kpre[2], vpre[2];
  auto gload = [&](int t) {
    const size_t g0 = zb + (size_t)(t * KB) * E3;
#pragma unroll
    for (int c = 0; c < 2; ++c) {
      const int row = c0row + c * 32;
      kpre[c] = *(const bf16x8*)&Z[g0 + (size_t)row * E3 + kcol0 + c0col];
      vpre[c] = *(const bf16x8*)&Z[g0 + (size_t)row * E3 + vcol0 + c0col];
    }
  };
  auto lwrite = [&](int buf) {
#pragma unroll
    for (int c = 0; c < 2; ++c) {
      *(bf16x8*)&sK[buf][c0row + c * 32][c0col] = kpre[c];
#pragma unroll
      for (int j = 0; j < 8; ++j)
        sVT[buf][c0col + j][c0row + c * 32] = vpre[c][j];
    }
  };

#pragma unroll 1
  for (int phase = 0; phase < 2; ++phase) {
    const int qtile = phase == 0 ? blockIdx.x : (15 - blockIdx.x);
    const int q0    = qtile * QB;
    const int qwave = q0 + w * 32;
    const int T     = 2 * qtile + 2;   // KV tiles this phase

    // Q fragments (B-operand of swapped QK^T)
    bf16x8 qf[2][2];
#pragma unroll
    for (int qs = 0; qs < 2; ++qs) {
      const int qrow = qwave + qs * 16 + l15;
#pragma unroll
      for (int kk = 0; kk < 2; ++kk)
        qf[qs][kk] = *(const bf16x8*)&Z[zb + (size_t)qrow * E3 + qcol0 + kk * 32 + lhi * 8];
    }

    f32x4 accO[2][4];
    f32x4 accL[2];
#pragma unroll
    for (int qs = 0; qs < 2; ++qs) {
#pragma unroll
      for (int dt = 0; dt < 4; ++dt) accO[qs][dt] = z4;
      accL[qs] = z4;
    }
    float mrow[2] = {-1e30f, -1e30f};

    // pipeline prologue: tile 0 into buf 0; tile 1 into regs
    gload(0);
    lwrite(0);
    if (T > 1) gload(1);
    __syncthreads();

#pragma unroll 1
    for (int t = 0; t < T; ++t) {
      const int cur = t & 1;
      if (t + 1 < T) lwrite(cur ^ 1);     // tile t+1 regs -> other buffer
      if (t + 2 < T) gload(t + 2);        // issue next prefetch early

      const bool active = (t * KB <= qwave + 31);
      union PB { unsigned int u[4]; bf16x8 v; };
      PB pb[2][2];

      if (active) {
        // S^T = K·Q^T
        f32x4 st[2][4];
#pragma unroll
        for (int qs = 0; qs < 2; ++qs)
#pragma unroll
          for (int kt = 0; kt < 4; ++kt) st[qs][kt] = z4;
#pragma unroll
        for (int kt = 0; kt < 4; ++kt)
#pragma unroll
          for (int kk = 0; kk < 2; ++kk) {
            bf16x8 kf = *(const bf16x8*)&sK[cur][kt * 16 + l15][kk * 32 + lhi * 8];
#pragma unroll
            for (int qs = 0; qs < 2; ++qs)
              st[qs][kt] = __builtin_amdgcn_mfma_f32_16x16x32_bf16(kf, qf[qs][kk], st[qs][kt], 0, 0, 0);
          }

        const bool needmask = (t * KB + KB - 1) > qwave;
        float sv[2][16];
        float mxs[2];

#pragma unroll
        for (int qs = 0; qs < 2; ++qs) {
#pragma unroll
          for (int i = 0; i < 16; ++i) sv[qs][i] = st[qs][i >> 2][i & 3];
          if (needmask) {
            const int qg = qwave + qs * 16 + l15;
#pragma unroll
            for (int i = 0; i < 16; ++i) {
              const int kg = t * KB + (i >> 2) * 16 + lhi * 4 + (i & 3);
              if (kg > qg) sv[qs][i] = -1e32f;
            }
          }
          float m0 = fmaxf(sv[qs][0], sv[qs][1]);
          float m1 = fmaxf(sv[qs][2], sv[qs][3]);
          float m2 = fmaxf(sv[qs][4], sv[qs][5]);
          float m3 = fmaxf(sv[qs][6], sv[qs][7]);
          float m4 = fmaxf(sv[qs][8], sv[qs][9]);
          float m5 = fmaxf(sv[qs][10], sv[qs][11]);
          float m6 = fmaxf(sv[qs][12], sv[qs][13]);
          float m7 = fmaxf(sv[qs][14], sv[qs][15]);
          float mr = fmaxf(fmaxf(fmaxf(m0, m1), fmaxf(m2, m3)),
                           fmaxf(fmaxf(m4, m5), fmaxf(m6, m7)));
          mr = fmaxf(mr, __shfl_xor(mr, 16));
          mr = fmaxf(mr, __shfl_xor(mr, 32));
          mxs[qs] = mr * scale;
        }

        const bool grow = (mxs[0] > mrow[0] + DEFER) || (mxs[1] > mrow[1] + DEFER);
        if (__any(grow)) {
#pragma unroll
          for (int qs = 0; qs < 2; ++qs) {
            const float mnew  = fmaxf(mrow[qs], mxs[qs]);
            const float alpha = exp2f((mrow[qs] - mnew) * L2E);
            mrow[qs] = mnew;
#pragma unroll
            for (int dt = 0; dt < 4; ++dt) accO[qs][dt] *= alpha;
            accL[qs] *= alpha;
          }
        }

#pragma unroll
        for (int qs = 0; qs < 2; ++qs) {
          const float mm = -mrow[qs] * L2E;
#pragma unroll
          for (int c = 0; c < 2; ++c)
#pragma unroll
            for (int i = 0; i < 4; ++i) {
              const float p0 = exp2f(fmaf(sv[qs][c * 8 + 2 * i],     SL2E, mm));
              const float p1 = exp2f(fmaf(sv[qs][c * 8 + 2 * i + 1], SL2E, mm));
              const bf16 b0 = (bf16)p0;
              const bf16 b1 = (bf16)p1;
              pb[qs][c].u[i] = (unsigned int)__builtin_bit_cast(unsigned short, b0)
                             | ((unsigned int)__builtin_bit_cast(unsigned short, b1) << 16);
            }
        }

        // denominator via ones-MFMA
#pragma unroll
        for (int c = 0; c < 2; ++c)
#pragma unroll
          for (int qs = 0; qs < 2; ++qs)
            accL[qs] = __builtin_amdgcn_mfma_f32_16x16x32_bf16(onesf, pb[qs][c].v, accL[qs], 0, 0, 0);

        // O^T += V^T·P^T with the permuted k-map
#pragma unroll
        for (int c = 0; c < 2; ++c) {
#pragma unroll
          for (int dt = 0; dt < 4; ++dt) {
            const u32x2 a0 = *(const u32x2*)&sVT[cur][dt * 16 + l15][c * 32 + lhi * 4];
            const u32x2 a1 = *(const u32x2*)&sVT[cur][dt * 16 + l15][c * 32 + 16 + lhi * 4];
            const u32x4 avu = {a0[0], a0[1], a1[0], a1[1]};
            const bf16x8 av = __builtin_bit_cast(bf16x8, avu);
#pragma unroll
            for (int qs = 0; qs < 2; ++qs)
              accO[qs][dt] = __builtin_amdgcn_mfma_f32_16x16x32_bf16(av, pb[qs][c].v, accO[qs][dt], 0, 0, 0);
          }
        }
      }

      __syncthreads();   // the ONLY barrier: separates buf reads/writes across iters
    }

    // phase epilogue: normalize, float4 stores
#pragma unroll
    for (int qs = 0; qs < 2; ++qs) {
      const float inv  = 1.f / accL[qs][0];
      const int   qrow = qwave + qs * 16 + l15;
#pragma unroll
      for (int dt = 0; dt < 4; ++dt) {
        float4 o;
        o.x = accO[qs][dt][0] * inv;
        o.y = accO[qs][dt][1] * inv;
        o.z = accO[qs][dt][2] * inv;
        o.w = accO[qs][dt][3] * inv;
        *(float4*)&out[ob + (size_t)qrow * DM + h * HD + dt * 16 + lhi * 4] = o;
      }
    }
  }
}

extern "C" void kernel_launch(void* const* d_in, const int* in_sizes, int n_in,
                              void* d_out, int out_size, void* d_ws, size_t ws_size,
                              hipStream_t stream) {
  const float* x    = (const float*)d_in[0];
  const float* W    = (const float*)d_in[1];
  const float* bias = (const float*)d_in[2];
  float* out = (float*)d_out;

  bf16* xb = (bf16*)d_ws;
  bf16* Wb = xb + (size_t)NBAT * SEQ * DM;
  bf16* Zb = Wb + (size_t)E3 * DM;

  cvt_bf16_kernel<<<1024, 256, 0, stream>>>(x, xb, NBAT * SEQ * DM / 8);
  cvt_bf16_kernel<<<512, 256, 0, stream>>>(W, Wb, E3 * DM / 8);

  dim3 g1(NBAT * SEQ / BM, E3 / BN);
  qkv_gemm_kernel<<<g1, 256, 0, stream>>>(xb, Wb, bias, Zb);

  dim3 g2(SEQ / (2 * QB), NH, NBAT);   // 8 pair-blocks: qtile b then 15-b
  attn_kernel<<<g2, 256, 0, stream>>>(Zb, out);
}

// Round 8
// 169.119 us; speedup vs baseline: 1.5421x; 1.0380x over previous
//
#include <hip/hip_runtime.h>
#include <hip/hip_bf16.h>

typedef __bf16 bf16;
typedef __bf16 bf16x4 __attribute__((ext_vector_type(4)));
typedef __bf16 bf16x8 __attribute__((ext_vector_type(8)));
typedef float f32x4 __attribute__((ext_vector_type(4)));
typedef unsigned int u32x2 __attribute__((ext_vector_type(2)));
typedef unsigned int u32x4 __attribute__((ext_vector_type(4)));

#define SEQ   2048
#define NBAT  4
#define DM    1024
#define NH    16
#define HD    64
#define E3    3072

// ---------------- fp32 -> bf16 convert (x and W fused in one launch) ----------------
__global__ void cvt2_bf16_kernel(const float* __restrict__ a, bf16* __restrict__ oa, int na8,
                                 const float* __restrict__ b, bf16* __restrict__ ob, int nb8) {
  const int stride = gridDim.x * blockDim.x;
  const int ntot = na8 + nb8;
  for (int i = blockIdx.x * blockDim.x + threadIdx.x; i < ntot; i += stride) {
    const float* src;
    bf16* dst;
    int j;
    if (i < na8) { src = a; dst = oa; j = i; }
    else         { src = b; dst = ob; j = i - na8; }
    const float4* p = (const float4*)(src + (size_t)j * 8);
    float4 x = p[0];
    float4 y = p[1];
    bf16x8 o;
    o[0] = (bf16)x.x; o[1] = (bf16)x.y; o[2] = (bf16)x.z; o[3] = (bf16)x.w;
    o[4] = (bf16)y.x; o[5] = (bf16)y.y; o[6] = (bf16)y.z; o[7] = (bf16)y.w;
    *(bf16x8*)(dst + (size_t)j * 8) = o;
  }
}

// ---------------- QKV projection GEMM: Z = X * W^T + b ----------------
#define BM 128
#define BN 128
#define BK 32
#define KSTEPS (DM / BK)

__global__ __launch_bounds__(256, 2) void qkv_gemm_kernel(
    const bf16* __restrict__ A, const bf16* __restrict__ B,
    const float* __restrict__ bias, bf16* __restrict__ Z)
{
  __shared__ bf16 sA[2][BM * BK];
  __shared__ bf16 sB[2][BN * BK];

  const int tid  = threadIdx.x;
  const int lane = tid & 63;
  const int w    = tid >> 6;
  const int wr   = w >> 1;
  const int wc   = w & 1;
  const int m0   = blockIdx.x * BM;
  const int n0   = blockIdx.y * BN;

  const f32x4 z4 = {0.f, 0.f, 0.f, 0.f};
  f32x4 acc[4][4];
#pragma unroll
  for (int i = 0; i < 4; ++i)
#pragma unroll
    for (int j = 0; j < 4; ++j)
      acc[i][j] = z4;

  const int srow = w * 32 + (lane >> 2);
  const int skk  = (lane & 3) * 8;
  const bf16* gA = A + (size_t)m0 * DM;
  const bf16* gB = B + (size_t)n0 * DM;

  auto stage = [&](int buf, int t) {
    const int k0 = t * BK;
#pragma unroll
    for (int c = 0; c < 2; ++c)
      __builtin_amdgcn_global_load_lds(
          (const __attribute__((address_space(1))) unsigned int*)(gA + (size_t)(srow + c * 16) * DM + k0 + skk),
          (__attribute__((address_space(3))) unsigned int*)(&sA[buf][w * 1024 + c * 512]),
          16, 0, 0);
#pragma unroll
    for (int c = 0; c < 2; ++c)
      __builtin_amdgcn_global_load_lds(
          (const __attribute__((address_space(1))) unsigned int*)(gB + (size_t)(srow + c * 16) * DM + k0 + skk),
          (__attribute__((address_space(3))) unsigned int*)(&sB[buf][w * 1024 + c * 512]),
          16, 0, 0);
  };

  stage(0, 0);
  int cur = 0;
  const int arow = wr * 64 + (lane & 15);
  const int brow = wc * 64 + (lane & 15);
  const int kf   = (lane >> 4) * 8;

  for (int t = 0; t < KSTEPS; ++t) {
    __syncthreads();
    if (t + 1 < KSTEPS) stage(cur ^ 1, t + 1);
    bf16x8 af[4], bfr[4];
#pragma unroll
    for (int i = 0; i < 4; ++i)
      af[i] = *(const bf16x8*)&sA[cur][(arow + i * 16) * BK + kf];
#pragma unroll
    for (int j = 0; j < 4; ++j)
      bfr[j] = *(const bf16x8*)&sB[cur][(brow + j * 16) * BK + kf];
#pragma unroll
    for (int i = 0; i < 4; ++i)
#pragma unroll
      for (int j = 0; j < 4; ++j)
        acc[i][j] = __builtin_amdgcn_mfma_f32_16x16x32_bf16(af[i], bfr[j], acc[i][j], 0, 0, 0);
    cur ^= 1;
  }

#pragma unroll
  for (int i = 0; i < 4; ++i) {
#pragma unroll
    for (int j = 0; j < 4; ++j) {
      const int col = n0 + wc * 64 + j * 16 + (lane & 15);
      const float bb = bias[col];
#pragma unroll
      for (int r = 0; r < 4; ++r) {
        const int row = m0 + wr * 64 + i * 16 + (lane >> 4) * 4 + r;
        Z[(size_t)row * E3 + col] = (bf16)(acc[i][j][r] + bb);
      }
    }
  }
}

// ---------------- causal flash attention ----------------
// 8 waves x 16 q-rows (512 threads). Swapped QK^T: S^T = K·Q^T, q = lane&15.
// PV k-permutation k = c*32 + (j>>2)*16 + lhi*4 + (j&3):
//   B-frag (P^T) == lane's own softmax registers, A-frag (V^T) from sVT.
// Pair-scheduled causal: block b does qtile b then qtile 15-b -> uniform 34
// tile-iterations. Single barrier per tile; double-buffered sK/sVT; V^T
// written directly from prefetch registers.
#define QB 128
#define KB 64
#define KPK 72   // sK stride (bf16): 144B, b128-aligned
#define KPV 68   // sVT stride (bf16): 136B, b64-aligned

__global__ __launch_bounds__(512, 4) void attn_kernel(
    const bf16* __restrict__ Z, float* __restrict__ out)
{
  __shared__ bf16 sK[2][KB][KPK];
  __shared__ bf16 sVT[2][HD][KPV];   // sVT[buf][d][k]

  const int tid   = threadIdx.x;
  const int lane  = tid & 63;
  const int w     = tid >> 6;        // 0..7
  const int l15   = lane & 15;
  const int lhi   = lane >> 4;
  const int h     = blockIdx.y;
  const int n     = blockIdx.z;

  const size_t zb = (size_t)n * SEQ * E3;
  const int kcol0 = h * HD;
  const int qcol0 = DM + h * HD;
  const int vcol0 = 2 * DM + h * HD;

  const f32x4 z4 = {0.f, 0.f, 0.f, 0.f};
  const float scale = 0.03125f;   // D^-0.5 = 1/32 (full model dim)
  const float L2E   = 1.4426950408889634f;
  const float SL2E  = scale * L2E;
  const float DEFER = 4.0f;

  const u32x4 onesu = {0x3F803F80u, 0x3F803F80u, 0x3F803F80u, 0x3F803F80u};
  const bf16x8 onesf = __builtin_bit_cast(bf16x8, onesu);

  // staging map: thread owns k-row c0row, d-cols c0col..c0col+7
  const int c0row = tid >> 3;          // 0..63
  const int c0col = (tid & 7) * 8;

  const size_t ob = (size_t)n * SEQ * DM;

  bf16x8 kpre, vpre;
  auto gload = [&](int t) {
    const size_t g0 = zb + (size_t)(t * KB + c0row) * E3;
    kpre = *(const bf16x8*)&Z[g0 + kcol0 + c0col];
    vpre = *(const bf16x8*)&Z[g0 + vcol0 + c0col];
  };
  auto lwrite = [&](int buf) {
    *(bf16x8*)&sK[buf][c0row][c0col] = kpre;
#pragma unroll
    for (int j = 0; j < 8; ++j)
      sVT[buf][c0col + j][c0row] = vpre[j];
  };

#pragma unroll 1
  for (int phase = 0; phase < 2; ++phase) {
    const int qtile = phase == 0 ? blockIdx.x : (15 - blockIdx.x);
    const int q0    = qtile * QB;
    const int qwave = q0 + w * 16;     // wave's 16 q-rows
    const int T     = 2 * qtile + 2;   // KV tiles this phase

    // Q fragments (B-operand of swapped QK^T)
    bf16x8 qf[2];
    {
      const int qrow = qwave + l15;
#pragma unroll
      for (int kk = 0; kk < 2; ++kk)
        qf[kk] = *(const bf16x8*)&Z[zb + (size_t)qrow * E3 + qcol0 + kk * 32 + lhi * 8];
    }

    f32x4 accO[4];
    f32x4 accL;
#pragma unroll
    for (int dt = 0; dt < 4; ++dt) accO[dt] = z4;
    accL = z4;
    float mrow = -1e30f;

    // pipeline prologue: tile 0 into buf 0; tile 1 into regs
    gload(0);
    lwrite(0);
    if (T > 1) gload(1);
    __syncthreads();

#pragma unroll 1
    for (int t = 0; t < T; ++t) {
      const int cur = t & 1;
      if (t + 1 < T) lwrite(cur ^ 1);     // tile t+1 regs -> other buffer
      if (t + 2 < T) gload(t + 2);        // issue next prefetch early

      const bool active = (t * KB <= qwave + 15);
      union PB { unsigned int u[4]; bf16x8 v; };
      PB pb[2];

      if (active) {
        // S^T = K·Q^T : C[k_local=lhi*4+r][q=l15] per kt
        f32x4 st[4];
#pragma unroll
        for (int kt = 0; kt < 4; ++kt) st[kt] = z4;
#pragma unroll
        for (int kt = 0; kt < 4; ++kt)
#pragma unroll
          for (int kk = 0; kk < 2; ++kk) {
            bf16x8 kf = *(const bf16x8*)&sK[cur][kt * 16 + l15][kk * 32 + lhi * 8];
            st[kt] = __builtin_amdgcn_mfma_f32_16x16x32_bf16(kf, qf[kk], st[kt], 0, 0, 0);
          }

        const bool needmask = (t * KB + KB - 1) > qwave;
        float sv[16];
#pragma unroll
        for (int i = 0; i < 16; ++i) sv[i] = st[i >> 2][i & 3];
        if (needmask) {
          const int qg = qwave + l15;
#pragma unroll
          for (int i = 0; i < 16; ++i) {
            const int kg = t * KB + (i >> 2) * 16 + lhi * 4 + (i & 3);
            if (kg > qg) sv[i] = -1e32f;
          }
        }
        float m0 = fmaxf(sv[0], sv[1]);
        float m1 = fmaxf(sv[2], sv[3]);
        float m2 = fmaxf(sv[4], sv[5]);
        float m3 = fmaxf(sv[6], sv[7]);
        float m4 = fmaxf(sv[8], sv[9]);
        float m5 = fmaxf(sv[10], sv[11]);
        float m6 = fmaxf(sv[12], sv[13]);
        float m7 = fmaxf(sv[14], sv[15]);
        float mr = fmaxf(fmaxf(fmaxf(m0, m1), fmaxf(m2, m3)),
                         fmaxf(fmaxf(m4, m5), fmaxf(m6, m7)));
        mr = fmaxf(mr, __shfl_xor(mr, 16));
        mr = fmaxf(mr, __shfl_xor(mr, 32));
        const float mxs = mr * scale;

        // defer-max: rescale only when the row max outgrew m+THR
        if (__any(mxs > mrow + DEFER)) {
          const float mnew  = fmaxf(mrow, mxs);
          const float alpha = exp2f((mrow - mnew) * L2E);
          mrow = mnew;
#pragma unroll
          for (int dt = 0; dt < 4; ++dt) accO[dt] *= alpha;
          accL *= alpha;
        }

        // p = exp2(fma(s_raw, scale*log2e, -m*log2e)), packed in pairs
        const float mm = -mrow * L2E;
#pragma unroll
        for (int c = 0; c < 2; ++c)
#pragma unroll
          for (int i = 0; i < 4; ++i) {
            const float p0 = exp2f(fmaf(sv[c * 8 + 2 * i],     SL2E, mm));
            const float p1 = exp2f(fmaf(sv[c * 8 + 2 * i + 1], SL2E, mm));
            const bf16 b0 = (bf16)p0;
            const bf16 b1 = (bf16)p1;
            pb[c].u[i] = (unsigned int)__builtin_bit_cast(unsigned short, b0)
                       | ((unsigned int)__builtin_bit_cast(unsigned short, b1) << 16);
          }

        // denominator via ones-MFMA
#pragma unroll
        for (int c = 0; c < 2; ++c)
          accL = __builtin_amdgcn_mfma_f32_16x16x32_bf16(onesf, pb[c].v, accL, 0, 0, 0);

        // O^T += V^T·P^T with the permuted k-map
#pragma unroll
        for (int c = 0; c < 2; ++c) {
#pragma unroll
          for (int dt = 0; dt < 4; ++dt) {
            const u32x2 a0 = *(const u32x2*)&sVT[cur][dt * 16 + l15][c * 32 + lhi * 4];
            const u32x2 a1 = *(const u32x2*)&sVT[cur][dt * 16 + l15][c * 32 + 16 + lhi * 4];
            const u32x4 avu = {a0[0], a0[1], a1[0], a1[1]};
            const bf16x8 av = __builtin_bit_cast(bf16x8, avu);
            accO[dt] = __builtin_amdgcn_mfma_f32_16x16x32_bf16(av, pb[c].v, accO[dt], 0, 0, 0);
          }
        }
      }

      __syncthreads();   // the ONLY barrier per tile
    }

    // phase epilogue: normalize, float4 stores
    {
      const float inv  = 1.f / accL[0];
      const int   qrow = qwave + l15;
#pragma unroll
      for (int dt = 0; dt < 4; ++dt) {
        float4 o;
        o.x = accO[dt][0] * inv;
        o.y = accO[dt][1] * inv;
        o.z = accO[dt][2] * inv;
        o.w = accO[dt][3] * inv;
        *(float4*)&out[ob + (size_t)qrow * DM + h * HD + dt * 16 + lhi * 4] = o;
      }
    }
  }
}

extern "C" void kernel_launch(void* const* d_in, const int* in_sizes, int n_in,
                              void* d_out, int out_size, void* d_ws, size_t ws_size,
                              hipStream_t stream) {
  const float* x    = (const float*)d_in[0];
  const float* W    = (const float*)d_in[1];
  const float* bias = (const float*)d_in[2];
  float* out = (float*)d_out;

  bf16* xb = (bf16*)d_ws;
  bf16* Wb = xb + (size_t)NBAT * SEQ * DM;
  bf16* Zb = Wb + (size_t)E3 * DM;

  cvt2_bf16_kernel<<<1536, 256, 0, stream>>>(x, xb, NBAT * SEQ * DM / 8,
                                             W, Wb, E3 * DM / 8);

  dim3 g1(NBAT * SEQ / BM, E3 / BN);
  qkv_gemm_kernel<<<g1, 256, 0, stream>>>(xb, Wb, bias, Zb);

  dim3 g2(SEQ / (2 * QB), NH, NBAT);   // 8 pair-blocks: qtile b then 15-b
  attn_kernel<<<g2, 512, 0, stream>>>(Zb, out);
}

// Round 9
// 167.420 us; speedup vs baseline: 1.5577x; 1.0101x over previous
//
#include <hip/hip_runtime.h>
#include <hip/hip_bf16.h>

typedef __bf16 bf16;
typedef __bf16 bf16x4 __attribute__((ext_vector_type(4)));
typedef __bf16 bf16x8 __attribute__((ext_vector_type(8)));
typedef float f32x4 __attribute__((ext_vector_type(4)));
typedef unsigned int u32x4 __attribute__((ext_vector_type(4)));

#define SEQ   2048
#define NBAT  4
#define DM    1024
#define NH    16
#define HD    64
#define E3    3072

// ---------------- fp32 -> bf16 convert (x and W fused in one launch) ----------------
__global__ void cvt2_bf16_kernel(const float* __restrict__ a, bf16* __restrict__ oa, int na8,
                                 const float* __restrict__ b, bf16* __restrict__ ob, int nb8) {
  const int stride = gridDim.x * blockDim.x;
  const int ntot = na8 + nb8;
  for (int i = blockIdx.x * blockDim.x + threadIdx.x; i < ntot; i += stride) {
    const float* src;
    bf16* dst;
    int j;
    if (i < na8) { src = a; dst = oa; j = i; }
    else         { src = b; dst = ob; j = i - na8; }
    const float4* p = (const float4*)(src + (size_t)j * 8);
    float4 x = p[0];
    float4 y = p[1];
    bf16x8 o;
    o[0] = (bf16)x.x; o[1] = (bf16)x.y; o[2] = (bf16)x.z; o[3] = (bf16)x.w;
    o[4] = (bf16)y.x; o[5] = (bf16)y.y; o[6] = (bf16)y.z; o[7] = (bf16)y.w;
    *(bf16x8*)(dst + (size_t)j * 8) = o;
  }
}

// ---------------- QKV projection GEMM: Z = X * W^T + b ----------------
#define BM 128
#define BN 128
#define BK 32
#define KSTEPS (DM / BK)

__global__ __launch_bounds__(256, 2) void qkv_gemm_kernel(
    const bf16* __restrict__ A, const bf16* __restrict__ B,
    const float* __restrict__ bias, bf16* __restrict__ Z)
{
  __shared__ bf16 sA[2][BM * BK];
  __shared__ bf16 sB[2][BN * BK];

  const int tid  = threadIdx.x;
  const int lane = tid & 63;
  const int w    = tid >> 6;
  const int wr   = w >> 1;
  const int wc   = w & 1;
  const int m0   = blockIdx.x * BM;
  const int n0   = blockIdx.y * BN;

  const f32x4 z4 = {0.f, 0.f, 0.f, 0.f};
  f32x4 acc[4][4];
#pragma unroll
  for (int i = 0; i < 4; ++i)
#pragma unroll
    for (int j = 0; j < 4; ++j)
      acc[i][j] = z4;

  const int srow = w * 32 + (lane >> 2);
  const int skk  = (lane & 3) * 8;
  const bf16* gA = A + (size_t)m0 * DM;
  const bf16* gB = B + (size_t)n0 * DM;

  auto stage = [&](int buf, int t) {
    const int k0 = t * BK;
#pragma unroll
    for (int c = 0; c < 2; ++c)
      __builtin_amdgcn_global_load_lds(
          (const __attribute__((address_space(1))) unsigned int*)(gA + (size_t)(srow + c * 16) * DM + k0 + skk),
          (__attribute__((address_space(3))) unsigned int*)(&sA[buf][w * 1024 + c * 512]),
          16, 0, 0);
#pragma unroll
    for (int c = 0; c < 2; ++c)
      __builtin_amdgcn_global_load_lds(
          (const __attribute__((address_space(1))) unsigned int*)(gB + (size_t)(srow + c * 16) * DM + k0 + skk),
          (__attribute__((address_space(3))) unsigned int*)(&sB[buf][w * 1024 + c * 512]),
          16, 0, 0);
  };

  stage(0, 0);
  int cur = 0;
  const int arow = wr * 64 + (lane & 15);
  const int brow = wc * 64 + (lane & 15);
  const int kf   = (lane >> 4) * 8;

  for (int t = 0; t < KSTEPS; ++t) {
    __syncthreads();
    if (t + 1 < KSTEPS) stage(cur ^ 1, t + 1);
    bf16x8 af[4], bfr[4];
#pragma unroll
    for (int i = 0; i < 4; ++i)
      af[i] = *(const bf16x8*)&sA[cur][(arow + i * 16) * BK + kf];
#pragma unroll
    for (int j = 0; j < 4; ++j)
      bfr[j] = *(const bf16x8*)&sB[cur][(brow + j * 16) * BK + kf];
#pragma unroll
    for (int i = 0; i < 4; ++i)
#pragma unroll
      for (int j = 0; j < 4; ++j)
        acc[i][j] = __builtin_amdgcn_mfma_f32_16x16x32_bf16(af[i], bfr[j], acc[i][j], 0, 0, 0);
    cur ^= 1;
  }

#pragma unroll
  for (int i = 0; i < 4; ++i) {
#pragma unroll
    for (int j = 0; j < 4; ++j) {
      const int col = n0 + wc * 64 + j * 16 + (lane & 15);
      const float bb = bias[col];
#pragma unroll
      for (int r = 0; r < 4; ++r) {
        const int row = m0 + wr * 64 + i * 16 + (lane >> 4) * 4 + r;
        Z[(size_t)row * E3 + col] = (bf16)(acc[i][j][r] + bb);
      }
    }
  }
}

// ---------------- causal flash attention ----------------
// 8 waves x 16 q-rows (512 threads). Swapped QK^T: S^T = K·Q^T, q = lane&15.
// PV k-permutation k(j) = c*32 + (j>>2)*16 + lhi*4 + (j&3); B-frag = lane's
// own softmax registers. sVT stores V[k][d] at [d][sigma(k) ^ X(d)] where
// sigma(32c+16b+4g+r) = 32c+8g+4b+r makes sigma(k(j)) = 32c+8*lhi+j
// (contiguous -> single b128 PV read) and X(d) = ((d^(d>>3))&7)<<3 spreads
// banks (writes 2/bank = free; reads at b128 BW floor).
// sK staged by global_load_lds with XOR block swizzle blk=(d>>3)^(k&7)
// applied via pre-swizzled per-lane global source (LDS dest stays linear).
// Pair-scheduled causal: block b does qtile b then 15-b (uniform 34 tiles).
// Single barrier per tile; double-buffered sK/sVT.
#define QB 128
#define KB 64

__global__ __launch_bounds__(512, 4) void attn_kernel(
    const bf16* __restrict__ Z, float* __restrict__ out)
{
  __shared__ bf16 sK[2][KB][64];    // [buf][k][swizzled d]
  __shared__ bf16 sVT[2][HD][64];   // [buf][d][sigma(k)^X(d)]

  const int tid   = threadIdx.x;
  const int lane  = tid & 63;
  const int w     = tid >> 6;        // 0..7
  const int l15   = lane & 15;
  const int lhi   = lane >> 4;
  const int l7    = l15 & 7;
  const int e2    = l15 >> 3;        // 0/1
  const int h     = blockIdx.y;
  const int n     = blockIdx.z;

  const size_t zb = (size_t)n * SEQ * E3;
  const int kcol0 = h * HD;
  const int qcol0 = DM + h * HD;
  const int vcol0 = 2 * DM + h * HD;

  const f32x4 z4 = {0.f, 0.f, 0.f, 0.f};
  const float scale = 0.03125f;   // D^-0.5 = 1/32 (full model dim)
  const float L2E   = 1.4426950408889634f;
  const float SL2E  = scale * L2E;
  const float DEFER = 4.0f;

  const u32x4 onesu = {0x3F803F80u, 0x3F803F80u, 0x3F803F80u, 0x3F803F80u};
  const bf16x8 onesf = __builtin_bit_cast(bf16x8, onesu);

  // V staging map: thread owns k-row c0row, d-cols c0col..c0col+7
  const int c0row = tid >> 3;          // 0..63
  const int t7    = tid & 7;
  const int c0col = t7 * 8;
  // sigma(c0row): 32c+16b+4g+r -> 32c+8g+4b+r
  const int sgk = (c0row & 32) | ((c0row & 12) << 1) | ((c0row & 16) >> 2) | (c0row & 3);

  // K staging map (global source pre-swizzle for global_load_lds)
  const int krow_off = 8 * w + (lane >> 3);            // k row within tile
  const int kdblk    = ((lane & 7) ^ (lane >> 3)) * 8; // swizzled d offset

  const size_t ob = (size_t)n * SEQ * DM;

  bf16x8 vpre;
  auto vload = [&](int t) {
    vpre = *(const bf16x8*)&Z[zb + (size_t)(t * KB + c0row) * E3 + vcol0 + c0col];
  };
  auto lwriteV = [&](int buf) {
#pragma unroll
    for (int j = 0; j < 8; ++j)
      sVT[buf][c0col + j][sgk ^ ((j ^ t7) << 3)] = vpre[j];
  };
  auto stageK = [&](int t, int buf) {
    __builtin_amdgcn_global_load_lds(
        (const __attribute__((address_space(1))) unsigned int*)(
            Z + zb + (size_t)(t * KB + krow_off) * E3 + kcol0 + kdblk),
        (__attribute__((address_space(3))) unsigned int*)(&sK[buf][8 * w][0]),
        16, 0, 0);
  };

#pragma unroll 1
  for (int phase = 0; phase < 2; ++phase) {
    const int qtile = phase == 0 ? blockIdx.x : (15 - blockIdx.x);
    const int q0    = qtile * QB;
    const int qwave = q0 + w * 16;     // wave's 16 q-rows
    const int T     = 2 * qtile + 2;   // KV tiles this phase

    // Q fragments (B-operand of swapped QK^T)
    bf16x8 qf[2];
    {
      const int qrow = qwave + l15;
#pragma unroll
      for (int kk = 0; kk < 2; ++kk)
        qf[kk] = *(const bf16x8*)&Z[zb + (size_t)qrow * E3 + qcol0 + kk * 32 + lhi * 8];
    }

    f32x4 accO[4];
    f32x4 accL;
#pragma unroll
    for (int dt = 0; dt < 4; ++dt) accO[dt] = z4;
    accL = z4;
    float mrow = -1e30f;

    // pipeline prologue: tile 0 into buf 0 (K via DMA, V via regs); tile 1 V into regs
    stageK(0, 0);
    vload(0);
    lwriteV(0);
    if (T > 1) vload(1);
    __syncthreads();

#pragma unroll 1
    for (int t = 0; t < T; ++t) {
      const int cur = t & 1;
      if (t + 1 < T) { stageK(t + 1, cur ^ 1); lwriteV(cur ^ 1); }
      if (t + 2 < T) vload(t + 2);

      const bool active = (t * KB <= qwave + 15);
      union PB { unsigned int u[4]; bf16x8 v; };
      PB pb[2];

      if (active) {
        // S^T = K·Q^T : C[k_local=lhi*4+r][q=l15] per kt
        f32x4 st[4];
#pragma unroll
        for (int kt = 0; kt < 4; ++kt) st[kt] = z4;
#pragma unroll
        for (int kt = 0; kt < 4; ++kt)
#pragma unroll
          for (int kk = 0; kk < 2; ++kk) {
            const int blk = ((4 * kk + lhi) ^ l7) * 8;
            bf16x8 kf = *(const bf16x8*)&sK[cur][kt * 16 + l15][blk];
            st[kt] = __builtin_amdgcn_mfma_f32_16x16x32_bf16(kf, qf[kk], st[kt], 0, 0, 0);
          }

        const bool needmask = (t * KB + KB - 1) > qwave;
        float sv[16];
#pragma unroll
        for (int i = 0; i < 16; ++i) sv[i] = st[i >> 2][i & 3];
        if (needmask) {
          const int qg = qwave + l15;
#pragma unroll
          for (int i = 0; i < 16; ++i) {
            const int kg = t * KB + (i >> 2) * 16 + lhi * 4 + (i & 3);
            if (kg > qg) sv[i] = -1e32f;
          }
        }
        float m0 = fmaxf(sv[0], sv[1]);
        float m1 = fmaxf(sv[2], sv[3]);
        float m2 = fmaxf(sv[4], sv[5]);
        float m3 = fmaxf(sv[6], sv[7]);
        float m4 = fmaxf(sv[8], sv[9]);
        float m5 = fmaxf(sv[10], sv[11]);
        float m6 = fmaxf(sv[12], sv[13]);
        float m7 = fmaxf(sv[14], sv[15]);
        float mr = fmaxf(fmaxf(fmaxf(m0, m1), fmaxf(m2, m3)),
                         fmaxf(fmaxf(m4, m5), fmaxf(m6, m7)));
        mr = fmaxf(mr, __shfl_xor(mr, 16));
        mr = fmaxf(mr, __shfl_xor(mr, 32));
        const float mxs = mr * scale;

        // defer-max: rescale only when the row max outgrew m+THR
        if (__any(mxs > mrow + DEFER)) {
          const float mnew  = fmaxf(mrow, mxs);
          const float alpha = exp2f((mrow - mnew) * L2E);
          mrow = mnew;
#pragma unroll
          for (int dt = 0; dt < 4; ++dt) accO[dt] *= alpha;
          accL *= alpha;
        }

        // p = exp2(fma(s_raw, scale*log2e, -m*log2e)), packed in pairs
        const float mm = -mrow * L2E;
#pragma unroll
        for (int c = 0; c < 2; ++c)
#pragma unroll
          for (int i = 0; i < 4; ++i) {
            const float p0 = exp2f(fmaf(sv[c * 8 + 2 * i],     SL2E, mm));
            const float p1 = exp2f(fmaf(sv[c * 8 + 2 * i + 1], SL2E, mm));
            const bf16 b0 = (bf16)p0;
            const bf16 b1 = (bf16)p1;
            pb[c].u[i] = (unsigned int)__builtin_bit_cast(unsigned short, b0)
                       | ((unsigned int)__builtin_bit_cast(unsigned short, b1) << 16);
          }

        // denominator via ones-MFMA
#pragma unroll
        for (int c = 0; c < 2; ++c)
          accL = __builtin_amdgcn_mfma_f32_16x16x32_bf16(onesf, pb[c].v, accL, 0, 0, 0);

        // O^T += V^T·P^T : av = single b128 (sigma-contiguous, XOR-swizzled)
#pragma unroll
        for (int c = 0; c < 2; ++c) {
#pragma unroll
          for (int dt = 0; dt < 4; ++dt) {
            const int Xv  = l7 ^ ((2 * dt + e2) & 7);
            const int idx = ((4 * c + lhi) ^ Xv) << 3;
            const bf16x8 av = *(const bf16x8*)&sVT[cur][dt * 16 + l15][idx];
            accO[dt] = __builtin_amdgcn_mfma_f32_16x16x32_bf16(av, pb[c].v, accO[dt], 0, 0, 0);
          }
        }
      }

      __syncthreads();   // the ONLY barrier per tile (drains DMA + orders buffers)
    }

    // phase epilogue: normalize, float4 stores
    {
      const float inv  = 1.f / accL[0];
      const int   qrow = qwave + l15;
#pragma unroll
      for (int dt = 0; dt < 4; ++dt) {
        float4 o;
        o.x = accO[dt][0] * inv;
        o.y = accO[dt][1] * inv;
        o.z = accO[dt][2] * inv;
        o.w = accO[dt][3] * inv;
        *(float4*)&out[ob + (size_t)qrow * DM + h * HD + dt * 16 + lhi * 4] = o;
      }
    }
  }
}

extern "C" void kernel_launch(void* const* d_in, const int* in_sizes, int n_in,
                              void* d_out, int out_size, void* d_ws, size_t ws_size,
                              hipStream_t stream) {
  const float* x    = (const float*)d_in[0];
  const float* W    = (const float*)d_in[1];
  const float* bias = (const float*)d_in[2];
  float* out = (float*)d_out;

  bf16* xb = (bf16*)d_ws;
  bf16* Wb = xb + (size_t)NBAT * SEQ * DM;
  bf16* Zb = Wb + (size_t)E3 * DM;

  cvt2_bf16_kernel<<<1536, 256, 0, stream>>>(x, xb, NBAT * SEQ * DM / 8,
                                             W, Wb, E3 * DM / 8);

  dim3 g1(NBAT * SEQ / BM, E3 / BN);
  qkv_gemm_kernel<<<g1, 256, 0, stream>>>(xb, Wb, bias, Zb);

  dim3 g2(SEQ / (2 * QB), NH, NBAT);   // 8 pair-blocks: qtile b then 15-b
  attn_kernel<<<g2, 512, 0, stream>>>(Zb, out);
}